// Round 9
// baseline (125.327 us; speedup 1.0000x reference)
//
#include <hip/hip_runtime.h>
#include <math.h>

#define NPTS 11
#define NSTEPS 10
#define METRIC_FLOOR 0.1f

typedef float v2f __attribute__((ext_vector_type(2)));

#define L2E 1.44269504088896340736f
#define LN2 0.69314718055994530942f

// Lane-pair exchange via DPP quad_perm [1,0,3,2] (0xB1): swaps lanes 0<->1,
// 2<->3 within each quad. Pure VALU, no LDS pipe.
static __device__ __forceinline__ float pswap(float x) {
    int i = __builtin_bit_cast(int, x);
    i = __builtin_amdgcn_mov_dpp(i, 0xB1, 0xF, 0xF, true);
    return __builtin_bit_cast(float, i);
}

static __device__ __forceinline__ float fast_tanh(float x) {
    float e = __builtin_amdgcn_exp2f(x * (2.0f * L2E));
    return fmaf(-2.0f, __builtin_amdgcn_rcpf(e + 1.0f), 1.0f);
}

// Per-lane HALF of the metric-MLP small weights (this lane's 8 neurons /
// 8 output columns). Lane-dependent values -> VGPRs.
struct MWh {
    float w1c[8], w1l[8], b1v[8], b2v[8], w3v[8];
};

// ---------------------------------------------------------------------------
// metric0h: value only, lane-pair split. Each lane: 8 hidden neurons (L1),
// partner's h via pswap (inline), 8 output columns of L2, z reduced via pswap.
// ---------------------------------------------------------------------------
static __device__ __forceinline__ float metric0h(
    float c, float lam, const MWh& mw,
    const float* __restrict__ rowsA, const float* __restrict__ rowsB,
    float b3v)
{
    float ho[8];
#pragma unroll
    for (int k = 0; k < 8; ++k) {
        float u = fmaf(c, mw.w1c[k], fmaf(lam, mw.w1l[k], mw.b1v[k]));
        ho[k] = fast_tanh(u);
    }

    v2f U[4];
#pragma unroll
    for (int jp = 0; jp < 4; ++jp) U[jp] = (v2f){mw.b2v[2*jp], mw.b2v[2*jp+1]};

#pragma unroll 2
    for (int k = 0; k < 8; ++k) {
        const float4* r = reinterpret_cast<const float4*>(rowsA + k * 16);
        float4 w0 = r[0], w1 = r[1];
        v2f hh = (v2f){ho[k], ho[k]};
        U[0] = __builtin_elementwise_fma((v2f){w0.x, w0.y}, hh, U[0]);
        U[1] = __builtin_elementwise_fma((v2f){w0.z, w0.w}, hh, U[1]);
        U[2] = __builtin_elementwise_fma((v2f){w1.x, w1.y}, hh, U[2]);
        U[3] = __builtin_elementwise_fma((v2f){w1.z, w1.w}, hh, U[3]);
    }
#pragma unroll 2
    for (int k = 0; k < 8; ++k) {
        const float4* r = reinterpret_cast<const float4*>(rowsB + k * 16);
        float4 w0 = r[0], w1 = r[1];
        float hxk = pswap(ho[k]);
        v2f hh = (v2f){hxk, hxk};
        U[0] = __builtin_elementwise_fma((v2f){w0.x, w0.y}, hh, U[0]);
        U[1] = __builtin_elementwise_fma((v2f){w0.z, w0.w}, hh, U[1]);
        U[2] = __builtin_elementwise_fma((v2f){w1.x, w1.y}, hh, U[2]);
        U[3] = __builtin_elementwise_fma((v2f){w1.z, w1.w}, hh, U[3]);
    }

    float zp = 0.0f;
#pragma unroll
    for (int jp = 0; jp < 4; ++jp) {
#pragma unroll
        for (int kk = 0; kk < 2; ++kk)
            zp = fmaf(fast_tanh(U[jp][kk]), mw.w3v[2*jp+kk], zp);
    }
    float z = b3v + zp + pswap(zp);

    float az = fabsf(z);
    float em = __builtin_amdgcn_exp2f(-az * L2E);
    float sp = fmaxf(z, 0.0f) + __builtin_amdgcn_logf(1.0f + em) * LN2;
    return sp + METRIC_FLOOR;
}

// ---------------------------------------------------------------------------
// gamma1h: Gamma = 0.5*(dg/dc)/g, lane-pair split (value + d/dc chains).
// Both lanes reconstruct identical full (z,dz) -> identical G (lockstep).
// ---------------------------------------------------------------------------
static __device__ __forceinline__ float gamma1h(
    float c, float lam, const MWh& mw,
    const float* __restrict__ rowsA, const float* __restrict__ rowsB,
    float b3v)
{
    float ho[8], po[8];
#pragma unroll
    for (int k = 0; k < 8; ++k) {
        float a  = mw.w1c[k];
        float u  = fmaf(c, a, fmaf(lam, mw.w1l[k], mw.b1v[k]));
        float t0 = fast_tanh(u);
        float s  = fmaf(-t0, t0, 1.0f);
        ho[k] = t0;
        po[k] = s * a;
    }

    v2f U[4], DU[4];
#pragma unroll
    for (int jp = 0; jp < 4; ++jp) {
        U[jp]  = (v2f){mw.b2v[2*jp], mw.b2v[2*jp+1]};
        DU[jp] = (v2f){0.0f, 0.0f};
    }
#pragma unroll 2
    for (int k = 0; k < 8; ++k) {
        const float4* r = reinterpret_cast<const float4*>(rowsA + k * 16);
        float4 w0 = r[0], w1 = r[1];
        v2f hh = (v2f){ho[k], ho[k]};
        v2f pp = (v2f){po[k], po[k]};
        v2f wa = (v2f){w0.x, w0.y}, wb = (v2f){w0.z, w0.w};
        v2f wc = (v2f){w1.x, w1.y}, wd = (v2f){w1.z, w1.w};
        U[0]  = __builtin_elementwise_fma(wa, hh, U[0]);
        DU[0] = __builtin_elementwise_fma(wa, pp, DU[0]);
        U[1]  = __builtin_elementwise_fma(wb, hh, U[1]);
        DU[1] = __builtin_elementwise_fma(wb, pp, DU[1]);
        U[2]  = __builtin_elementwise_fma(wc, hh, U[2]);
        DU[2] = __builtin_elementwise_fma(wc, pp, DU[2]);
        U[3]  = __builtin_elementwise_fma(wd, hh, U[3]);
        DU[3] = __builtin_elementwise_fma(wd, pp, DU[3]);
    }
#pragma unroll 2
    for (int k = 0; k < 8; ++k) {
        const float4* r = reinterpret_cast<const float4*>(rowsB + k * 16);
        float4 w0 = r[0], w1 = r[1];
        float hxk = pswap(ho[k]);
        float pxk = pswap(po[k]);
        v2f hh = (v2f){hxk, hxk};
        v2f pp = (v2f){pxk, pxk};
        v2f wa = (v2f){w0.x, w0.y}, wb = (v2f){w0.z, w0.w};
        v2f wc = (v2f){w1.x, w1.y}, wd = (v2f){w1.z, w1.w};
        U[0]  = __builtin_elementwise_fma(wa, hh, U[0]);
        DU[0] = __builtin_elementwise_fma(wa, pp, DU[0]);
        U[1]  = __builtin_elementwise_fma(wb, hh, U[1]);
        DU[1] = __builtin_elementwise_fma(wb, pp, DU[1]);
        U[2]  = __builtin_elementwise_fma(wc, hh, U[2]);
        DU[2] = __builtin_elementwise_fma(wc, pp, DU[2]);
        U[3]  = __builtin_elementwise_fma(wd, hh, U[3]);
        DU[3] = __builtin_elementwise_fma(wd, pp, DU[3]);
    }

    float zp = 0.0f, dzp = 0.0f;
#pragma unroll
    for (int jp = 0; jp < 4; ++jp) {
#pragma unroll
        for (int kk = 0; kk < 2; ++kk) {
            float u  = U[jp][kk];
            float du = DU[jp][kk];
            float t0 = fast_tanh(u);
            float s  = fmaf(-t0, t0, 1.0f);
            float w3 = mw.w3v[2*jp+kk];
            zp  = fmaf(t0, w3, zp);
            dzp = fmaf(s * du, w3, dzp);
        }
    }
    float z  = b3v + zp + pswap(zp);
    float dz = dzp + pswap(dzp);

    // softplus + sigmoid sharing one exp: em = exp(-|z|), r = 1/(1+em),
    // sig = z>=0 ? r : 1-r.
    float az  = fabsf(z);
    float em  = __builtin_amdgcn_exp2f(-az * L2E);
    float r1  = __builtin_amdgcn_rcpf(1.0f + em);
    float sp  = fmaxf(z, 0.0f) + __builtin_amdgcn_logf(1.0f + em) * LN2;
    float sig = (z >= 0.0f) ? r1 : (1.0f - r1);
    float g   = sp + METRIC_FLOOR;
    return 0.5f * (sig * dz) * __builtin_amdgcn_rcpf(g);
}

extern "C" __global__ __launch_bounds__(256)
__attribute__((amdgpu_waves_per_eu(2, 2)))
void geodesic_kernel(const float* __restrict__ gc0, const float* __restrict__ gc1,
                     const float* __restrict__ glam,
                     const float* __restrict__ W1, const float* __restrict__ b1,
                     const float* __restrict__ W2, const float* __restrict__ b2,
                     const float* __restrict__ W3, const float* __restrict__ b3,
                     const float* __restrict__ D1, const float* __restrict__ d1,
                     const float* __restrict__ D2, const float* __restrict__ d2,
                     float* __restrict__ out, int n)
{
    __shared__ __align__(16) float sW2[256];
    __shared__ __align__(16) float sD1[6 * 64];
    __shared__ __align__(16) float sd1[64];
    __shared__ __align__(16) float sD2[64];

    const int t = threadIdx.x;
    sW2[t] = W2[t];
    for (int i = t; i < 384; i += 256) sD1[i] = D1[i];
    if (t >= 64 && t < 128) sd1[t - 64] = d1[t - 64];
    if (t >= 128 && t < 192) sD2[t - 128] = D2[t - 128];
    __syncthreads();

    const int gid  = blockIdx.x * blockDim.x + t;
    const int e    = gid >> 1;       // element index (2 lanes per element)
    const int half = gid & 1;        // which 8-neuron half this lane owns
    if (e >= n) return;

    // This lane's half of the small weights (lane-dependent -> VGPRs).
    MWh mw;
    {
        const int b = 8 * half;
#pragma unroll
        for (int k = 0; k < 8; ++k) {
            mw.w1c[k] = W1[b + k];
            mw.w1l[k] = W1[16 + b + k];
            mw.b1v[k] = b1[b + k];
            mw.b2v[k] = b2[b + k];
            mw.w3v[k] = W3[b + k];
        }
    }
    const float b3v = b3[0];
    const float d2v = d2[0];

    // W2 row slices: own rows x own col-slice, partner rows x own col-slice.
    const float* rowsA = sW2 + (8 * half) * 16 + 8 * half;
    const float* rowsB = sW2 + (8 * (1 - half)) * 16 + 8 * half;

    const float c0  = gc0[e];
    const float c1  = gc1[e];
    const float lam = glam[e];

    const float dt  = 1.0f / (float)(NPTS - 1);
    const float hdt = 0.5f * dt;
    const float dt6 = dt / 6.0f;

    // ---------------- Analytic init: sqrt(g)*v conserved --------------------
    const float mqm = 0.5f * (c0 + c1), mqr = 0.5f * (c1 - c0);
    float K;
    {
        const float x0 = 0.1834346424956498f, w0 = 0.3626837833783620f;
        const float x1 = 0.5255324099163290f, w1 = 0.3137066458778873f;
        const float x2 = 0.7966664774136267f, w2 = 0.2223810344533745f;
        const float x3 = 0.9602898564975363f, w3q = 0.1012285362903763f;
        float s0 = sqrtf(metric0h(fmaf(mqr,  x0, mqm), lam, mw, rowsA, rowsB, b3v))
                 + sqrtf(metric0h(fmaf(mqr, -x0, mqm), lam, mw, rowsA, rowsB, b3v));
        float s1 = sqrtf(metric0h(fmaf(mqr,  x1, mqm), lam, mw, rowsA, rowsB, b3v))
                 + sqrtf(metric0h(fmaf(mqr, -x1, mqm), lam, mw, rowsA, rowsB, b3v));
        float s2 = sqrtf(metric0h(fmaf(mqr,  x2, mqm), lam, mw, rowsA, rowsB, b3v))
                 + sqrtf(metric0h(fmaf(mqr, -x2, mqm), lam, mw, rowsA, rowsB, b3v));
        float s3 = sqrtf(metric0h(fmaf(mqr,  x3, mqm), lam, mw, rowsA, rowsB, b3v))
                 + sqrtf(metric0h(fmaf(mqr, -x3, mqm), lam, mw, rowsA, rowsB, b3v));
        K = w0 * s0 + w1 * s1 + w2 * s2 + w3q * s3;
    }
    const float g0   = metric0h(c0, lam, mw, rowsA, rowsB, b3v);
    const float v0i  = (mqr * K) * rsqrtf(g0);

    // ---------------- Single RK4 pass + stats + sensitivity accumulators ----
    float csum, vsum, plen, vmax, cf, vf, cs2, va;
    {
        float c = c0, v = v0i;
        float cs = c0, vs = v0i, pl = 0.0f, vm = fabsf(v0i), cp = c0;
        float c2sum = 0.0f, vasum = 0.0f, k4v_last = 0.0f;
#pragma unroll 1
        for (int s = 0; s < NSTEPS; ++s) {
            float G1 = gamma1h(c, lam, mw, rowsA, rowsB, b3v);
            float k1c = v, k1v = -G1 * v * v;
            vasum = fmaf((float)s * dt, k1v, vasum);      // t_s * a_s
            float c2 = c + hdt * k1c, v2 = v + hdt * k1v;
            float G2 = gamma1h(c2, lam, mw, rowsA, rowsB, b3v);
            float k2c = v2, k2v = -G2 * v2 * v2;
            float c3 = c + hdt * k2c, v3 = v + hdt * k2v;
            float G3 = gamma1h(c3, lam, mw, rowsA, rowsB, b3v);
            float k3c = v3, k3v = -G3 * v3 * v3;
            float c4 = c + dt * k3c, v4 = v + dt * k3v;
            float G4 = gamma1h(c4, lam, mw, rowsA, rowsB, b3v);
            float k4c = v4, k4v = -G4 * v4 * v4;
            c += dt6 * (k1c + 2.0f * k2c + 2.0f * k3c + k4c);
            v += dt6 * (k1v + 2.0f * k2v + 2.0f * k3v + k4v);
            cs += c; vs += v;
            c2sum = fmaf((float)(s + 1) * dt, v, c2sum);  // t_{s+1} * v_{s+1}
            pl += fabsf(c - cp); cp = c;
            vm = fmaxf(vm, fabsf(v));
            k4v_last = k4v;
        }
        vasum += k4v_last;                                // t_10 = 1, a_10 ~ k4v
        csum = cs; vsum = vs; plen = pl; vmax = vm; cf = c; vf = v;
        cs2 = c2sum; va = vasum;
    }

    // ---------------- First-order correction to the Newton root -------------
    float vf_safe = (fabsf(vf) < 1e-6f) ? ((vf >= 0.0f) ? 1e-6f : -1e-6f) : vf;
    float eps = (c1 - cf) * __builtin_amdgcn_rcpf(vf_safe);
    float csum_c = fmaf(eps, cs2, csum);
    float vsum_c = fmaf(eps, vsum + va, vsum);
    float plen_c = plen + ((vf >= 0.0f) ? (c1 - cf) : (cf - c1));
    float vmax_c = fmaf(eps, vmax, vmax);
    float cf_c   = cf + eps * vf_safe;                    // == c1

    // ---------------- Decoder: feats(6) -> 64 tanh -> 1 (split 32/32) -------
    const float inv_npts = 1.0f / (float)NPTS;
    const float f0 = csum_c * inv_npts;
    const float f1 = cf_c;
    const float f2 = plen_c;
    const float f3 = vsum_c * inv_npts;
    const float f4 = vmax_c;
    const float f5 = lam;

    const int jb = 32 * half;
    float accp = 0.0f;
#pragma unroll 4
    for (int k = 0; k < 32; ++k) {
        int j = jb + k;
        float u = sd1[j];
        u = fmaf(f0, sD1[0 * 64 + j], u);
        u = fmaf(f1, sD1[1 * 64 + j], u);
        u = fmaf(f2, sD1[2 * 64 + j], u);
        u = fmaf(f3, sD1[3 * 64 + j], u);
        u = fmaf(f4, sD1[4 * 64 + j], u);
        u = fmaf(f5, sD1[5 * 64 + j], u);
        accp = fmaf(fast_tanh(u), sD2[j], accp);
    }
    float acc = d2v + accp + pswap(accp);
    if (half == 0) out[e] = acc;
}

extern "C" void kernel_launch(void* const* d_in, const int* in_sizes, int n_in,
                              void* d_out, int out_size, void* d_ws, size_t ws_size,
                              hipStream_t stream) {
    const float* c_source   = (const float*)d_in[0];
    const float* c_target   = (const float*)d_in[1];
    const float* wavelength = (const float*)d_in[2];
    const float* W1 = (const float*)d_in[3];
    const float* b1 = (const float*)d_in[4];
    const float* W2 = (const float*)d_in[5];
    const float* b2 = (const float*)d_in[6];
    const float* W3 = (const float*)d_in[7];
    const float* b3 = (const float*)d_in[8];
    const float* D1 = (const float*)d_in[9];
    const float* d1 = (const float*)d_in[10];
    const float* D2 = (const float*)d_in[11];
    const float* d2 = (const float*)d_in[12];
    float* out = (float*)d_out;

    const int n = in_sizes[0];
    const int block = 256;
    const long long threads = 2LL * n;           // 2 lanes per element
    const int grid = (int)((threads + block - 1) / block);
    hipLaunchKernelGGL(geodesic_kernel, dim3(grid), dim3(block), 0, stream,
                       c_source, c_target, wavelength,
                       W1, b1, W2, b2, W3, b3, D1, d1, D2, d2, out, n);
}

// Round 10
// 27.311 us; speedup vs baseline: 4.5889x; 4.5889x over previous
//
#include <hip/hip_runtime.h>
#include <math.h>

#define NPTS 11
#define NSTEPS 10
#define METRIC_FLOOR 0.1f

// Table geometry: NI intervals on [0,1], points at (j-1)/NI for j=0..NI+2
// (one border cell each side for the Catmull-Rom stencil + RK4 overshoot).
#define NI  84
#define NPT 87            // NI + 3 points per dim
#define NPT2 (NPT * NPT)  // 7569
#define WS_SG_OFF 8192    // float offset of sqrt(g) table in d_ws

typedef float v2f __attribute__((ext_vector_type(2)));

#define L2E 1.44269504088896340736f
#define LN2 0.69314718055994530942f

struct MW {
    float w1c[16], w1l[16], b1v[16], b2v[16], w3v[16];
};

static __device__ __forceinline__ float fast_tanh(float x) {
    float e = __builtin_amdgcn_exp2f(x * (2.0f * L2E));
    return fmaf(-2.0f, __builtin_amdgcn_rcpf(e + 1.0f), 1.0f);
}

// ---------------------------------------------------------------------------
// Full-accuracy MLP evals (PRECOMPUTE KERNEL ONLY — 7.6K threads, cost ~0)
// ---------------------------------------------------------------------------
static __device__ __forceinline__ float metric0(
    float c, float lam, const MW& mw, const float* __restrict__ sW2, float b3v)
{
    float h1[16];
#pragma unroll
    for (int j = 0; j < 16; ++j) {
        float u = fmaf(c, mw.w1c[j], fmaf(lam, mw.w1l[j], mw.b1v[j]));
        h1[j] = fast_tanh(u);
    }
    v2f U[8];
#pragma unroll
    for (int jp = 0; jp < 8; ++jp) U[jp] = (v2f){mw.b2v[2*jp], mw.b2v[2*jp+1]};
#pragma unroll 2
    for (int i = 0; i < 16; ++i) {
        const float4* wrow4 = reinterpret_cast<const float4*>(sW2 + i * 16);
        v2f hh = (v2f){h1[i], h1[i]};
#pragma unroll
        for (int q4 = 0; q4 < 4; ++q4) {
            float4 w4 = wrow4[q4];
            U[2*q4]   = __builtin_elementwise_fma((v2f){w4.x, w4.y}, hh, U[2*q4]);
            U[2*q4+1] = __builtin_elementwise_fma((v2f){w4.z, w4.w}, hh, U[2*q4+1]);
        }
    }
    float z = b3v;
#pragma unroll
    for (int jp = 0; jp < 8; ++jp)
#pragma unroll
        for (int k = 0; k < 2; ++k)
            z = fmaf(fast_tanh(U[jp][k]), mw.w3v[2*jp+k], z);
    float az = fabsf(z);
    float em = __builtin_amdgcn_exp2f(-az * L2E);
    float sp = fmaxf(z, 0.0f) + __builtin_amdgcn_logf(1.0f + em) * LN2;
    return sp + METRIC_FLOOR;
}

static __device__ __forceinline__ float gamma1(
    float c, float lam, const MW& mw, const float* __restrict__ sW2, float b3v)
{
    float h1[16], p1[16];
#pragma unroll
    for (int j = 0; j < 16; ++j) {
        float a  = mw.w1c[j];
        float u  = fmaf(c, a, fmaf(lam, mw.w1l[j], mw.b1v[j]));
        float t0 = fast_tanh(u);
        float s  = fmaf(-t0, t0, 1.0f);
        h1[j] = t0;
        p1[j] = s * a;
    }
    v2f U[8], DU[8];
#pragma unroll
    for (int jp = 0; jp < 8; ++jp) {
        U[jp]  = (v2f){mw.b2v[2*jp], mw.b2v[2*jp+1]};
        DU[jp] = (v2f){0.0f, 0.0f};
    }
#pragma unroll 2
    for (int i = 0; i < 16; ++i) {
        const float4* wrow4 = reinterpret_cast<const float4*>(sW2 + i * 16);
        v2f hh = (v2f){h1[i], h1[i]};
        v2f pp = (v2f){p1[i], p1[i]};
#pragma unroll
        for (int q4 = 0; q4 < 4; ++q4) {
            float4 w4 = wrow4[q4];
            v2f wa = (v2f){w4.x, w4.y};
            v2f wb = (v2f){w4.z, w4.w};
            int jp = 2 * q4;
            U[jp]    = __builtin_elementwise_fma(wa, hh, U[jp]);
            DU[jp]   = __builtin_elementwise_fma(wa, pp, DU[jp]);
            U[jp+1]  = __builtin_elementwise_fma(wb, hh, U[jp+1]);
            DU[jp+1] = __builtin_elementwise_fma(wb, pp, DU[jp+1]);
        }
    }
    float z = b3v, dz = 0.0f;
#pragma unroll
    for (int jp = 0; jp < 8; ++jp)
#pragma unroll
        for (int k = 0; k < 2; ++k) {
            float u  = U[jp][k];
            float du = DU[jp][k];
            float t0 = fast_tanh(u);
            float s  = fmaf(-t0, t0, 1.0f);
            float w3 = mw.w3v[2*jp+k];
            z  = fmaf(t0, w3, z);
            dz = fmaf(s * du, w3, dz);
        }
    float az  = fabsf(z);
    float em  = __builtin_amdgcn_exp2f(-az * L2E);
    float sp  = fmaxf(z, 0.0f) + __builtin_amdgcn_logf(1.0f + em) * LN2;
    float sig = __builtin_amdgcn_rcpf(1.0f + __builtin_amdgcn_exp2f(-z * L2E));
    float g   = sp + METRIC_FLOOR;
    return 0.5f * (sig * dz) * __builtin_amdgcn_rcpf(g);
}

// ---------------------------------------------------------------------------
// Precompute kernel: tabulate Gamma(c,lam) and sqrt(g(c,lam)) on the grid.
// ---------------------------------------------------------------------------
extern "C" __global__ void table_kernel(
    const float* __restrict__ W1, const float* __restrict__ b1,
    const float* __restrict__ W2, const float* __restrict__ b2,
    const float* __restrict__ W3, const float* __restrict__ b3,
    float* __restrict__ ws)
{
    __shared__ __align__(16) float sW2[256];
    const int t = threadIdx.x;
    sW2[t] = W2[t];
    __syncthreads();

    const int p = blockIdx.x * 256 + t;
    if (p >= NPT2) return;

    MW mw;
#pragma unroll
    for (int j = 0; j < 16; ++j) {
        mw.w1c[j] = W1[j];
        mw.w1l[j] = W1[16 + j];
        mw.b1v[j] = b1[j];
        mw.b2v[j] = b2[j];
        mw.w3v[j] = W3[j];
    }
    const float b3v = b3[0];

    const int j = p / NPT;          // lam index
    const int i = p - j * NPT;      // c index
    const float h = 1.0f / (float)NI;
    const float c   = (float)(i - 1) * h;
    const float lam = (float)(j - 1) * h;

    ws[p]             = gamma1(c, lam, mw, sW2, b3v);
    ws[WS_SG_OFF + p] = sqrtf(metric0(c, lam, mw, sW2, b3v));
}

// ---------------------------------------------------------------------------
// Catmull-Rom along c, with lam-row weights hoisted per thread.
// r0 = table + j0*NPT (first of 4 consecutive lam rows).
// ---------------------------------------------------------------------------
static __device__ __forceinline__ float ceval(
    const float* __restrict__ r0,
    float wy0, float wy1, float wy2, float wy3, float x)
{
    float sx = x * (float)NI;
    float fx = floorf(sx);
    fx = fminf(fmaxf(fx, 0.0f), (float)(NI - 1));
    float tx = sx - fx;
    int i0 = (int)fx;
    float tx2 = tx * tx;
    float w0 = 0.5f * tx * ((2.0f - tx) * tx - 1.0f);
    float w1 = 0.5f * (tx2 * (3.0f * tx - 5.0f) + 2.0f);
    float w2 = 0.5f * tx * ((4.0f - 3.0f * tx) * tx + 1.0f);
    float w3 = 0.5f * tx2 * (tx - 1.0f);
    const float* a = r0 + i0;
    float v0 = fmaf(w3, a[3], fmaf(w2, a[2], fmaf(w1, a[1], w0 * a[0])));
    a += NPT;
    float v1 = fmaf(w3, a[3], fmaf(w2, a[2], fmaf(w1, a[1], w0 * a[0])));
    a += NPT;
    float v2 = fmaf(w3, a[3], fmaf(w2, a[2], fmaf(w1, a[1], w0 * a[0])));
    a += NPT;
    float v3 = fmaf(w3, a[3], fmaf(w2, a[2], fmaf(w1, a[1], w0 * a[0])));
    return fmaf(wy3, v3, fmaf(wy2, v2, fmaf(wy1, v1, wy0 * v0)));
}

// ---------------------------------------------------------------------------
// Main kernel: table-driven integration + stats + decoder.
// ---------------------------------------------------------------------------
extern "C" __global__ __launch_bounds__(256, 1)
void geodesic_kernel(const float* __restrict__ gc0, const float* __restrict__ gc1,
                     const float* __restrict__ glam,
                     const float* __restrict__ D1, const float* __restrict__ d1,
                     const float* __restrict__ D2, const float* __restrict__ d2,
                     const float* __restrict__ ws,
                     float* __restrict__ out, int n)
{
    __shared__ float sG[NPT2];          // Gamma table
    __shared__ float sS[NPT2];          // sqrt(g) table
    __shared__ __align__(16) float sD1[6 * 64];
    __shared__ __align__(16) float sd1[64];
    __shared__ __align__(16) float sD2[64];

    const int t = threadIdx.x;
    for (int i = t; i < NPT2; i += 256) {
        sG[i] = ws[i];
        sS[i] = ws[WS_SG_OFF + i];
    }
    for (int i = t; i < 384; i += 256) sD1[i] = D1[i];
    if (t < 64) sd1[t] = d1[t];
    if (t >= 64 && t < 128) sD2[t - 64] = D2[t - 64];
    __syncthreads();

    const int idx = blockIdx.x * blockDim.x + t;
    if (idx >= n) return;

    const float d2v = d2[0];
    const float c0  = gc0[idx];
    const float c1  = gc1[idx];
    const float lam = glam[idx];

    // Hoist lam-row selection + Catmull-Rom weights (lam fixed per thread).
    float sy = lam * (float)NI;
    float fy = floorf(sy);
    fy = fminf(fmaxf(fy, 0.0f), (float)(NI - 1));
    float ty = sy - fy;
    int j0 = (int)fy;
    float ty2 = ty * ty;
    const float wy0 = 0.5f * ty * ((2.0f - ty) * ty - 1.0f);
    const float wy1 = 0.5f * (ty2 * (3.0f * ty - 5.0f) + 2.0f);
    const float wy2 = 0.5f * ty * ((4.0f - 3.0f * ty) * ty + 1.0f);
    const float wy3 = 0.5f * ty2 * (ty - 1.0f);
    const float* gr = sG + j0 * NPT;
    const float* sr = sS + j0 * NPT;

    const float dt  = 1.0f / (float)(NPTS - 1);
    const float hdt = 0.5f * dt;
    const float dt6 = dt / 6.0f;

    // ---------------- Analytic init: sqrt(g)*v conserved --------------------
    const float mqm = 0.5f * (c0 + c1), mqr = 0.5f * (c1 - c0);
    float K;
    {
        const float x0 = 0.1834346424956498f, w0 = 0.3626837833783620f;
        const float x1 = 0.5255324099163290f, w1 = 0.3137066458778873f;
        const float x2 = 0.7966664774136267f, w2 = 0.2223810344533745f;
        const float x3 = 0.9602898564975363f, w3q = 0.1012285362903763f;
        float s0 = ceval(sr, wy0, wy1, wy2, wy3, fmaf(mqr,  x0, mqm))
                 + ceval(sr, wy0, wy1, wy2, wy3, fmaf(mqr, -x0, mqm));
        float s1 = ceval(sr, wy0, wy1, wy2, wy3, fmaf(mqr,  x1, mqm))
                 + ceval(sr, wy0, wy1, wy2, wy3, fmaf(mqr, -x1, mqm));
        float s2 = ceval(sr, wy0, wy1, wy2, wy3, fmaf(mqr,  x2, mqm))
                 + ceval(sr, wy0, wy1, wy2, wy3, fmaf(mqr, -x2, mqm));
        float s3 = ceval(sr, wy0, wy1, wy2, wy3, fmaf(mqr,  x3, mqm))
                 + ceval(sr, wy0, wy1, wy2, wy3, fmaf(mqr, -x3, mqm));
        K = w0 * s0 + w1 * s1 + w2 * s2 + w3q * s3;
    }
    const float sg0 = ceval(sr, wy0, wy1, wy2, wy3, c0);
    const float v0i = (mqr * K) * __builtin_amdgcn_rcpf(sg0);

    // ---------------- Single RK4 pass + stats + sensitivity accumulators ----
    float csum, vsum, plen, vmax, cf, vf, cs2, va;
    {
        float c = c0, v = v0i;
        float cs = c0, vs = v0i, pl = 0.0f, vm = fabsf(v0i), cp = c0;
        float c2sum = 0.0f, vasum = 0.0f, k4v_last = 0.0f;
#pragma unroll 1
        for (int s = 0; s < NSTEPS; ++s) {
            float G1 = ceval(gr, wy0, wy1, wy2, wy3, c);
            float k1c = v, k1v = -G1 * v * v;
            vasum = fmaf((float)s * dt, k1v, vasum);      // t_s * a_s
            float c2 = c + hdt * k1c, v2 = v + hdt * k1v;
            float G2 = ceval(gr, wy0, wy1, wy2, wy3, c2);
            float k2c = v2, k2v = -G2 * v2 * v2;
            float c3 = c + hdt * k2c, v3 = v + hdt * k2v;
            float G3 = ceval(gr, wy0, wy1, wy2, wy3, c3);
            float k3c = v3, k3v = -G3 * v3 * v3;
            float c4 = c + dt * k3c, v4 = v + dt * k3v;
            float G4 = ceval(gr, wy0, wy1, wy2, wy3, c4);
            float k4c = v4, k4v = -G4 * v4 * v4;
            c += dt6 * (k1c + 2.0f * k2c + 2.0f * k3c + k4c);
            v += dt6 * (k1v + 2.0f * k2v + 2.0f * k3v + k4v);
            cs += c; vs += v;
            c2sum = fmaf((float)(s + 1) * dt, v, c2sum);  // t_{s+1} * v_{s+1}
            pl += fabsf(c - cp); cp = c;
            vm = fmaxf(vm, fabsf(v));
            k4v_last = k4v;
        }
        vasum += k4v_last;                                // t_10 = 1, a_10 ~ k4v
        csum = cs; vsum = vs; plen = pl; vmax = vm; cf = c; vf = v;
        cs2 = c2sum; va = vasum;
    }

    // ---------------- First-order correction to the Newton root -------------
    float vf_safe = (fabsf(vf) < 1e-6f) ? ((vf >= 0.0f) ? 1e-6f : -1e-6f) : vf;
    float eps = (c1 - cf) * __builtin_amdgcn_rcpf(vf_safe);
    float csum_c = fmaf(eps, cs2, csum);
    float vsum_c = fmaf(eps, vsum + va, vsum);
    float plen_c = plen + ((vf >= 0.0f) ? (c1 - cf) : (cf - c1));
    float vmax_c = fmaf(eps, vmax, vmax);
    float cf_c   = cf + eps * vf_safe;                    // == c1

    // ---------------- Decoder: feats(6) -> 64 tanh -> 1 ----------------
    const float inv_npts = 1.0f / (float)NPTS;
    const float f0 = csum_c * inv_npts;
    const float f1 = cf_c;
    const float f2 = plen_c;
    const float f3 = vsum_c * inv_npts;
    const float f4 = vmax_c;
    const float f5 = lam;

    float acc = d2v;
#pragma unroll 4
    for (int j = 0; j < 64; ++j) {
        float u = sd1[j];
        u = fmaf(f0, sD1[0 * 64 + j], u);
        u = fmaf(f1, sD1[1 * 64 + j], u);
        u = fmaf(f2, sD1[2 * 64 + j], u);
        u = fmaf(f3, sD1[3 * 64 + j], u);
        u = fmaf(f4, sD1[4 * 64 + j], u);
        u = fmaf(f5, sD1[5 * 64 + j], u);
        acc = fmaf(fast_tanh(u), sD2[j], acc);
    }
    out[idx] = acc;
}

extern "C" void kernel_launch(void* const* d_in, const int* in_sizes, int n_in,
                              void* d_out, int out_size, void* d_ws, size_t ws_size,
                              hipStream_t stream) {
    const float* c_source   = (const float*)d_in[0];
    const float* c_target   = (const float*)d_in[1];
    const float* wavelength = (const float*)d_in[2];
    const float* W1 = (const float*)d_in[3];
    const float* b1 = (const float*)d_in[4];
    const float* W2 = (const float*)d_in[5];
    const float* b2 = (const float*)d_in[6];
    const float* W3 = (const float*)d_in[7];
    const float* b3 = (const float*)d_in[8];
    const float* D1 = (const float*)d_in[9];
    const float* d1 = (const float*)d_in[10];
    const float* D2 = (const float*)d_in[11];
    const float* d2 = (const float*)d_in[12];
    float* out = (float*)d_out;
    float* ws  = (float*)d_ws;

    const int n = in_sizes[0];

    // Pass 1: tabulate Gamma and sqrt(g) (7569 points, 2 tables).
    const int tblocks = (NPT2 + 255) / 256;
    hipLaunchKernelGGL(table_kernel, dim3(tblocks), dim3(256), 0, stream,
                       W1, b1, W2, b2, W3, b3, ws);

    // Pass 2: table-driven geodesic solve + decoder.
    const int block = 256;
    const int grid  = (n + block - 1) / block;
    hipLaunchKernelGGL(geodesic_kernel, dim3(grid), dim3(block), 0, stream,
                       c_source, c_target, wavelength,
                       D1, d1, D2, d2, ws, out, n);
}

// Round 11
// 26.964 us; speedup vs baseline: 4.6479x; 1.0129x over previous
//
#include <hip/hip_runtime.h>
#include <math.h>

#define NPTS 11
#define NSTEPS 10
#define METRIC_FLOOR 0.1f

// Gamma Hermite grid: NG x NG points, point i at c=(i-1)/SCALE_G (1-pt border).
#define NG 56
#define SCALE_G 53.0f
// Raw grid for central differences: NR = NG+2, point ri at c=(ri-2)/SCALE_G.
#define NR 58
#define NR2 (NR * NR)        // 3364
// sqrt(g) bilinear grid: NS x NS points, point i at c=i/(NS-1).
#define NS 48
#define NS2 (NS * NS)        // 2304
#define SCALE_S 47.0f

// d_ws float offsets
#define WS_RAW 0             // raw Gamma grid, NR2 floats
#define WS_SG  4096          // sqrt(g) grid, NS2 floats
#define WS_H4  8192          // Hermite float4 table, NG*NG*4 floats

typedef float v2f __attribute__((ext_vector_type(2)));

#define L2E 1.44269504088896340736f
#define LN2 0.69314718055994530942f

struct MW {
    float w1c[16], w1l[16], b1v[16], b2v[16], w3v[16];
};

static __device__ __forceinline__ float fast_tanh(float x) {
    float e = __builtin_amdgcn_exp2f(x * (2.0f * L2E));
    return fmaf(-2.0f, __builtin_amdgcn_rcpf(e + 1.0f), 1.0f);
}

// ---------------------------------------------------------------------------
// Full-accuracy MLP evals (precompute kernels only)
// ---------------------------------------------------------------------------
static __device__ __forceinline__ float metric0(
    float c, float lam, const MW& mw, const float* __restrict__ sW2, float b3v)
{
    float h1[16];
#pragma unroll
    for (int j = 0; j < 16; ++j) {
        float u = fmaf(c, mw.w1c[j], fmaf(lam, mw.w1l[j], mw.b1v[j]));
        h1[j] = fast_tanh(u);
    }
    v2f U[8];
#pragma unroll
    for (int jp = 0; jp < 8; ++jp) U[jp] = (v2f){mw.b2v[2*jp], mw.b2v[2*jp+1]};
#pragma unroll 2
    for (int i = 0; i < 16; ++i) {
        const float4* wrow4 = reinterpret_cast<const float4*>(sW2 + i * 16);
        v2f hh = (v2f){h1[i], h1[i]};
#pragma unroll
        for (int q4 = 0; q4 < 4; ++q4) {
            float4 w4 = wrow4[q4];
            U[2*q4]   = __builtin_elementwise_fma((v2f){w4.x, w4.y}, hh, U[2*q4]);
            U[2*q4+1] = __builtin_elementwise_fma((v2f){w4.z, w4.w}, hh, U[2*q4+1]);
        }
    }
    float z = b3v;
#pragma unroll
    for (int jp = 0; jp < 8; ++jp)
#pragma unroll
        for (int k = 0; k < 2; ++k)
            z = fmaf(fast_tanh(U[jp][k]), mw.w3v[2*jp+k], z);
    float az = fabsf(z);
    float em = __builtin_amdgcn_exp2f(-az * L2E);
    float sp = fmaxf(z, 0.0f) + __builtin_amdgcn_logf(1.0f + em) * LN2;
    return sp + METRIC_FLOOR;
}

static __device__ __forceinline__ float gamma1(
    float c, float lam, const MW& mw, const float* __restrict__ sW2, float b3v)
{
    float h1[16], p1[16];
#pragma unroll
    for (int j = 0; j < 16; ++j) {
        float a  = mw.w1c[j];
        float u  = fmaf(c, a, fmaf(lam, mw.w1l[j], mw.b1v[j]));
        float t0 = fast_tanh(u);
        float s  = fmaf(-t0, t0, 1.0f);
        h1[j] = t0;
        p1[j] = s * a;
    }
    v2f U[8], DU[8];
#pragma unroll
    for (int jp = 0; jp < 8; ++jp) {
        U[jp]  = (v2f){mw.b2v[2*jp], mw.b2v[2*jp+1]};
        DU[jp] = (v2f){0.0f, 0.0f};
    }
#pragma unroll 2
    for (int i = 0; i < 16; ++i) {
        const float4* wrow4 = reinterpret_cast<const float4*>(sW2 + i * 16);
        v2f hh = (v2f){h1[i], h1[i]};
        v2f pp = (v2f){p1[i], p1[i]};
#pragma unroll
        for (int q4 = 0; q4 < 4; ++q4) {
            float4 w4 = wrow4[q4];
            v2f wa = (v2f){w4.x, w4.y};
            v2f wb = (v2f){w4.z, w4.w};
            int jp = 2 * q4;
            U[jp]    = __builtin_elementwise_fma(wa, hh, U[jp]);
            DU[jp]   = __builtin_elementwise_fma(wa, pp, DU[jp]);
            U[jp+1]  = __builtin_elementwise_fma(wb, hh, U[jp+1]);
            DU[jp+1] = __builtin_elementwise_fma(wb, pp, DU[jp+1]);
        }
    }
    float z = b3v, dz = 0.0f;
#pragma unroll
    for (int jp = 0; jp < 8; ++jp)
#pragma unroll
        for (int k = 0; k < 2; ++k) {
            float u  = U[jp][k];
            float du = DU[jp][k];
            float t0 = fast_tanh(u);
            float s  = fmaf(-t0, t0, 1.0f);
            float w3 = mw.w3v[2*jp+k];
            z  = fmaf(t0, w3, z);
            dz = fmaf(s * du, w3, dz);
        }
    float az  = fabsf(z);
    float em  = __builtin_amdgcn_exp2f(-az * L2E);
    float sp  = fmaxf(z, 0.0f) + __builtin_amdgcn_logf(1.0f + em) * LN2;
    float sig = __builtin_amdgcn_rcpf(1.0f + __builtin_amdgcn_exp2f(-z * L2E));
    float g   = sp + METRIC_FLOOR;
    return 0.5f * (sig * dz) * __builtin_amdgcn_rcpf(g);
}

// ---------------------------------------------------------------------------
// K1: raw Gamma grid (NR x NR) + sqrt(g) grid (NS x NS).
// ---------------------------------------------------------------------------
extern "C" __global__ void table_raw_kernel(
    const float* __restrict__ W1, const float* __restrict__ b1,
    const float* __restrict__ W2, const float* __restrict__ b2,
    const float* __restrict__ W3, const float* __restrict__ b3,
    float* __restrict__ ws)
{
    __shared__ __align__(16) float sW2[256];
    const int t = threadIdx.x;
    sW2[t] = W2[t];
    __syncthreads();

    const int p = blockIdx.x * 256 + t;
    if (p >= NR2 + NS2) return;

    MW mw;
#pragma unroll
    for (int j = 0; j < 16; ++j) {
        mw.w1c[j] = W1[j];
        mw.w1l[j] = W1[16 + j];
        mw.b1v[j] = b1[j];
        mw.b2v[j] = b2[j];
        mw.w3v[j] = W3[j];
    }
    const float b3v = b3[0];

    if (p < NR2) {
        const int j = p / NR, i = p - j * NR;
        const float c   = (float)(i - 2) / SCALE_G;
        const float lam = (float)(j - 2) / SCALE_G;
        ws[WS_RAW + p] = gamma1(c, lam, mw, sW2, b3v);
    } else {
        const int q = p - NR2;
        const int j = q / NS, i = q - j * NS;
        const float c   = (float)i / SCALE_S;
        const float lam = (float)j / SCALE_S;
        ws[WS_SG + q] = sqrtf(metric0(c, lam, mw, sW2, b3v));
    }
}

// ---------------------------------------------------------------------------
// K2: assemble Hermite float4 (f, f_c, f_lam, f_clam) via central differences.
// Hermite point i  <->  raw index ri = i+1 (always interior of raw grid).
// ---------------------------------------------------------------------------
extern "C" __global__ void table_hermite_kernel(float* __restrict__ ws)
{
    const int p = blockIdx.x * 256 + threadIdx.x;
    if (p >= NG * NG) return;
    const int j = p / NG, i = p - j * NG;
    const int ri = i + 1, rj = j + 1;
    const float* R = ws + WS_RAW;

    float f   = R[rj * NR + ri];
    float fc  = 0.5f  * (R[rj * NR + ri + 1] - R[rj * NR + ri - 1]);
    float fl  = 0.5f  * (R[(rj + 1) * NR + ri] - R[(rj - 1) * NR + ri]);
    float fcl = 0.25f * (R[(rj + 1) * NR + ri + 1] - R[(rj + 1) * NR + ri - 1]
                       - R[(rj - 1) * NR + ri + 1] + R[(rj - 1) * NR + ri - 1]);
    float4* H = reinterpret_cast<float4*>(ws + WS_H4);
    H[p] = make_float4(f, fc, fl, fcl);
}

// ---------------------------------------------------------------------------
// Bicubic Hermite eval: 4 aligned float4 LDS reads + ~27 FMA.
// r0/r1 = rows j0, j0+1 of the float4 table; hy* = lam Hermite weights.
// ---------------------------------------------------------------------------
static __device__ __forceinline__ float heval(
    const float4* __restrict__ r0, const float4* __restrict__ r1,
    float hy0, float hy1, float hy2, float hy3, float x)
{
    float sx = fmaf(x, SCALE_G, 1.0f);
    float fx = floorf(sx);
    fx = fminf(fmaxf(fx, 0.0f), (float)(NG - 2));
    float tx = sx - fx;
    int i0 = (int)fx;
    float t2 = tx * tx, t3 = t2 * tx;
    float hx0 = fmaf(2.0f, t3, fmaf(-3.0f, t2, 1.0f));
    float hx1 = t3 - 2.0f * t2 + tx;
    float hx2 = fmaf(-2.0f, t3, 3.0f * t2);
    float hx3 = t3 - t2;
    float4 p00 = r0[i0], p10 = r0[i0 + 1];
    float4 p01 = r1[i0], p11 = r1[i0 + 1];
    float A0 = fmaf(hx0, p00.x, fmaf(hx1, p00.y, fmaf(hx2, p10.x, hx3 * p10.y)));
    float B0 = fmaf(hx0, p00.z, fmaf(hx1, p00.w, fmaf(hx2, p10.z, hx3 * p10.w)));
    float A1 = fmaf(hx0, p01.x, fmaf(hx1, p01.y, fmaf(hx2, p11.x, hx3 * p11.y)));
    float B1 = fmaf(hx0, p01.z, fmaf(hx1, p01.w, fmaf(hx2, p11.z, hx3 * p11.w)));
    return fmaf(hy0, A0, fmaf(hy1, B0, fmaf(hy2, A1, hy3 * B1)));
}

// Bilinear sqrt(g): rows s0/s1, ty hoisted.
static __device__ __forceinline__ float seval(
    const float* __restrict__ s0, const float* __restrict__ s1,
    float ty, float x)
{
    float sx = x * SCALE_S;
    float fx = fminf(fmaxf(floorf(sx), 0.0f), SCALE_S - 1.0f);
    float tx = sx - fx;
    int i0 = (int)fx;
    float a = fmaf(tx, s0[i0 + 1] - s0[i0], s0[i0]);
    float b = fmaf(tx, s1[i0 + 1] - s1[i0], s1[i0]);
    return fmaf(ty, b - a, a);
}

// ---------------------------------------------------------------------------
// Main kernel: table-driven single-pass integration + stats + decoder.
// ---------------------------------------------------------------------------
extern "C" __global__ __launch_bounds__(256, 1)
void geodesic_kernel(const float* __restrict__ gc0, const float* __restrict__ gc1,
                     const float* __restrict__ glam,
                     const float* __restrict__ D1, const float* __restrict__ d1,
                     const float* __restrict__ D2, const float* __restrict__ d2,
                     const float* __restrict__ ws,
                     float* __restrict__ out, int n)
{
    __shared__ __align__(16) float4 sH[NG * NG];   // 50.2 KB
    __shared__ __align__(16) float  sS[NS2];       //  9.2 KB
    __shared__ __align__(16) float  sD1[6 * 64];
    __shared__ __align__(16) float  sd1[64];
    __shared__ __align__(16) float  sD2[64];

    const int t = threadIdx.x;
    const float4* wsH = reinterpret_cast<const float4*>(ws + WS_H4);
    for (int i = t; i < NG * NG; i += 256) sH[i] = wsH[i];
    for (int i = t; i < NS2; i += 256) sS[i] = ws[WS_SG + i];
    for (int i = t; i < 384; i += 256) sD1[i] = D1[i];
    if (t < 64) sd1[t] = d1[t];
    if (t >= 64 && t < 128) sD2[t - 64] = D2[t - 64];
    __syncthreads();

    const int idx = blockIdx.x * blockDim.x + t;
    if (idx >= n) return;

    const float d2v = d2[0];
    const float c0  = gc0[idx];
    const float c1  = gc1[idx];
    const float lam = glam[idx];

    // Hoist lam-direction Hermite row + weights.
    float sy = fmaf(lam, SCALE_G, 1.0f);
    float fy = fminf(fmaxf(floorf(sy), 0.0f), (float)(NG - 2));
    float ty = sy - fy;
    int j0 = (int)fy;
    float ty2 = ty * ty, ty3 = ty2 * ty;
    const float hy0 = fmaf(2.0f, ty3, fmaf(-3.0f, ty2, 1.0f));
    const float hy1 = ty3 - 2.0f * ty2 + ty;
    const float hy2 = fmaf(-2.0f, ty3, 3.0f * ty2);
    const float hy3 = ty3 - ty2;
    const float4* gr0 = sH + j0 * NG;
    const float4* gr1 = gr0 + NG;

    // Hoist lam row for sqrt(g) bilinear.
    float syl = lam * SCALE_S;
    float fyl = fminf(fmaxf(floorf(syl), 0.0f), SCALE_S - 1.0f);
    float tyl = syl - fyl;
    const float* sr0 = sS + (int)fyl * NS;
    const float* sr1 = sr0 + NS;

    const float dt  = 1.0f / (float)(NPTS - 1);
    const float hdt = 0.5f * dt;
    const float dt6 = dt / 6.0f;

    // ---------------- Analytic init: sqrt(g)*v conserved --------------------
    const float mqm = 0.5f * (c0 + c1), mqr = 0.5f * (c1 - c0);
    float K;
    {
        const float x0 = 0.1834346424956498f, w0 = 0.3626837833783620f;
        const float x1 = 0.5255324099163290f, w1 = 0.3137066458778873f;
        const float x2 = 0.7966664774136267f, w2 = 0.2223810344533745f;
        const float x3 = 0.9602898564975363f, w3q = 0.1012285362903763f;
        float s0 = seval(sr0, sr1, tyl, fmaf(mqr,  x0, mqm))
                 + seval(sr0, sr1, tyl, fmaf(mqr, -x0, mqm));
        float s1 = seval(sr0, sr1, tyl, fmaf(mqr,  x1, mqm))
                 + seval(sr0, sr1, tyl, fmaf(mqr, -x1, mqm));
        float s2 = seval(sr0, sr1, tyl, fmaf(mqr,  x2, mqm))
                 + seval(sr0, sr1, tyl, fmaf(mqr, -x2, mqm));
        float s3 = seval(sr0, sr1, tyl, fmaf(mqr,  x3, mqm))
                 + seval(sr0, sr1, tyl, fmaf(mqr, -x3, mqm));
        K = w0 * s0 + w1 * s1 + w2 * s2 + w3q * s3;
    }
    const float sg0 = seval(sr0, sr1, tyl, c0);
    const float v0i = (mqr * K) * __builtin_amdgcn_rcpf(sg0);

    // ---------------- Single RK4 pass + stats + sensitivity accumulators ----
    float csum, vsum, plen, vmax, cf, vf, cs2, va;
    {
        float c = c0, v = v0i;
        float cs = c0, vs = v0i, pl = 0.0f, vm = fabsf(v0i), cp = c0;
        float c2sum = 0.0f, vasum = 0.0f, k4v_last = 0.0f;
#pragma unroll 1
        for (int s = 0; s < NSTEPS; ++s) {
            float G1 = heval(gr0, gr1, hy0, hy1, hy2, hy3, c);
            float k1c = v, k1v = -G1 * v * v;
            vasum = fmaf((float)s * dt, k1v, vasum);      // t_s * a_s
            float c2 = c + hdt * k1c, v2 = v + hdt * k1v;
            float G2 = heval(gr0, gr1, hy0, hy1, hy2, hy3, c2);
            float k2c = v2, k2v = -G2 * v2 * v2;
            float c3 = c + hdt * k2c, v3 = v + hdt * k2v;
            float G3 = heval(gr0, gr1, hy0, hy1, hy2, hy3, c3);
            float k3c = v3, k3v = -G3 * v3 * v3;
            float c4 = c + dt * k3c, v4 = v + dt * k3v;
            float G4 = heval(gr0, gr1, hy0, hy1, hy2, hy3, c4);
            float k4c = v4, k4v = -G4 * v4 * v4;
            c += dt6 * (k1c + 2.0f * k2c + 2.0f * k3c + k4c);
            v += dt6 * (k1v + 2.0f * k2v + 2.0f * k3v + k4v);
            cs += c; vs += v;
            c2sum = fmaf((float)(s + 1) * dt, v, c2sum);  // t_{s+1} * v_{s+1}
            pl += fabsf(c - cp); cp = c;
            vm = fmaxf(vm, fabsf(v));
            k4v_last = k4v;
        }
        vasum += k4v_last;                                // t_10 = 1, a_10 ~ k4v
        csum = cs; vsum = vs; plen = pl; vmax = vm; cf = c; vf = v;
        cs2 = c2sum; va = vasum;
    }

    // ---------------- First-order correction to the Newton root -------------
    float vf_safe = (fabsf(vf) < 1e-6f) ? ((vf >= 0.0f) ? 1e-6f : -1e-6f) : vf;
    float eps = (c1 - cf) * __builtin_amdgcn_rcpf(vf_safe);
    float csum_c = fmaf(eps, cs2, csum);
    float vsum_c = fmaf(eps, vsum + va, vsum);
    float plen_c = plen + ((vf >= 0.0f) ? (c1 - cf) : (cf - c1));
    float vmax_c = fmaf(eps, vmax, vmax);
    float cf_c   = cf + eps * vf_safe;                    // == c1

    // ---------------- Decoder: feats(6) -> 64 tanh -> 1 ----------------
    const float inv_npts = 1.0f / (float)NPTS;
    const float f0 = csum_c * inv_npts;
    const float f1 = cf_c;
    const float f2 = plen_c;
    const float f3 = vsum_c * inv_npts;
    const float f4 = vmax_c;
    const float f5 = lam;

    float acc = d2v;
#pragma unroll 4
    for (int j = 0; j < 64; ++j) {
        float u = sd1[j];
        u = fmaf(f0, sD1[0 * 64 + j], u);
        u = fmaf(f1, sD1[1 * 64 + j], u);
        u = fmaf(f2, sD1[2 * 64 + j], u);
        u = fmaf(f3, sD1[3 * 64 + j], u);
        u = fmaf(f4, sD1[4 * 64 + j], u);
        u = fmaf(f5, sD1[5 * 64 + j], u);
        acc = fmaf(fast_tanh(u), sD2[j], acc);
    }
    out[idx] = acc;
}

extern "C" void kernel_launch(void* const* d_in, const int* in_sizes, int n_in,
                              void* d_out, int out_size, void* d_ws, size_t ws_size,
                              hipStream_t stream) {
    const float* c_source   = (const float*)d_in[0];
    const float* c_target   = (const float*)d_in[1];
    const float* wavelength = (const float*)d_in[2];
    const float* W1 = (const float*)d_in[3];
    const float* b1 = (const float*)d_in[4];
    const float* W2 = (const float*)d_in[5];
    const float* b2 = (const float*)d_in[6];
    const float* W3 = (const float*)d_in[7];
    const float* b3 = (const float*)d_in[8];
    const float* D1 = (const float*)d_in[9];
    const float* d1 = (const float*)d_in[10];
    const float* D2 = (const float*)d_in[11];
    const float* d2 = (const float*)d_in[12];
    float* out = (float*)d_out;
    float* ws  = (float*)d_ws;

    const int n = in_sizes[0];

    // K1: raw Gamma grid + sqrt(g) grid.
    const int p1 = NR2 + NS2;
    hipLaunchKernelGGL(table_raw_kernel, dim3((p1 + 255) / 256), dim3(256), 0,
                       stream, W1, b1, W2, b2, W3, b3, ws);
    // K2: Hermite float4 assembly.
    hipLaunchKernelGGL(table_hermite_kernel, dim3((NG * NG + 255) / 256),
                       dim3(256), 0, stream, ws);
    // Main.
    const int block = 256;
    const int grid  = (n + block - 1) / block;
    hipLaunchKernelGGL(geodesic_kernel, dim3(grid), dim3(block), 0, stream,
                       c_source, c_target, wavelength,
                       D1, d1, D2, d2, ws, out, n);
}

// Round 12
// 21.961 us; speedup vs baseline: 5.7068x; 1.2278x over previous
//
#include <hip/hip_runtime.h>
#include <math.h>

#define NPTS 11
#define NSTEPS 10
#define METRIC_FLOOR 0.1f

// Gamma Hermite grid: NG x NG points, point i at c=(i-1)/SCALE_G (1-pt border).
#define NG 56
#define SCALE_G 53.0f
// Raw grid for central differences: NR = NG+2, point ri at c=(ri-2)/SCALE_G.
#define NR 58
#define NR2 (NR * NR)        // 3364
// sqrt(g) bilinear grid: NS x NS points, point i at c=i/(NS-1).
#define NS 48
#define NS2 (NS * NS)        // 2304
#define SCALE_S 47.0f

// d_ws float offsets
#define WS_RAW 0             // raw Gamma grid, NR2 floats
#define WS_SG  4096          // sqrt(g) grid, NS2 floats
#define WS_H4  8192          // Hermite float4 table, NG*NG*4 floats

typedef float v2f __attribute__((ext_vector_type(2)));

#define L2E 1.44269504088896340736f
#define LN2 0.69314718055994530942f

struct MW {
    float w1c[16], w1l[16], b1v[16], b2v[16], w3v[16];
};

static __device__ __forceinline__ float fast_tanh(float x) {
    float e = __builtin_amdgcn_exp2f(x * (2.0f * L2E));
    return fmaf(-2.0f, __builtin_amdgcn_rcpf(e + 1.0f), 1.0f);
}

// ---------------------------------------------------------------------------
// Full-accuracy MLP evals (precompute kernels only)
// ---------------------------------------------------------------------------
static __device__ __forceinline__ float metric0(
    float c, float lam, const MW& mw, const float* __restrict__ sW2, float b3v)
{
    float h1[16];
#pragma unroll
    for (int j = 0; j < 16; ++j) {
        float u = fmaf(c, mw.w1c[j], fmaf(lam, mw.w1l[j], mw.b1v[j]));
        h1[j] = fast_tanh(u);
    }
    v2f U[8];
#pragma unroll
    for (int jp = 0; jp < 8; ++jp) U[jp] = (v2f){mw.b2v[2*jp], mw.b2v[2*jp+1]};
#pragma unroll 2
    for (int i = 0; i < 16; ++i) {
        const float4* wrow4 = reinterpret_cast<const float4*>(sW2 + i * 16);
        v2f hh = (v2f){h1[i], h1[i]};
#pragma unroll
        for (int q4 = 0; q4 < 4; ++q4) {
            float4 w4 = wrow4[q4];
            U[2*q4]   = __builtin_elementwise_fma((v2f){w4.x, w4.y}, hh, U[2*q4]);
            U[2*q4+1] = __builtin_elementwise_fma((v2f){w4.z, w4.w}, hh, U[2*q4+1]);
        }
    }
    float z = b3v;
#pragma unroll
    for (int jp = 0; jp < 8; ++jp)
#pragma unroll
        for (int k = 0; k < 2; ++k)
            z = fmaf(fast_tanh(U[jp][k]), mw.w3v[2*jp+k], z);
    float az = fabsf(z);
    float em = __builtin_amdgcn_exp2f(-az * L2E);
    float sp = fmaxf(z, 0.0f) + __builtin_amdgcn_logf(1.0f + em) * LN2;
    return sp + METRIC_FLOOR;
}

static __device__ __forceinline__ float gamma1(
    float c, float lam, const MW& mw, const float* __restrict__ sW2, float b3v)
{
    float h1[16], p1[16];
#pragma unroll
    for (int j = 0; j < 16; ++j) {
        float a  = mw.w1c[j];
        float u  = fmaf(c, a, fmaf(lam, mw.w1l[j], mw.b1v[j]));
        float t0 = fast_tanh(u);
        float s  = fmaf(-t0, t0, 1.0f);
        h1[j] = t0;
        p1[j] = s * a;
    }
    v2f U[8], DU[8];
#pragma unroll
    for (int jp = 0; jp < 8; ++jp) {
        U[jp]  = (v2f){mw.b2v[2*jp], mw.b2v[2*jp+1]};
        DU[jp] = (v2f){0.0f, 0.0f};
    }
#pragma unroll 2
    for (int i = 0; i < 16; ++i) {
        const float4* wrow4 = reinterpret_cast<const float4*>(sW2 + i * 16);
        v2f hh = (v2f){h1[i], h1[i]};
        v2f pp = (v2f){p1[i], p1[i]};
#pragma unroll
        for (int q4 = 0; q4 < 4; ++q4) {
            float4 w4 = wrow4[q4];
            v2f wa = (v2f){w4.x, w4.y};
            v2f wb = (v2f){w4.z, w4.w};
            int jp = 2 * q4;
            U[jp]    = __builtin_elementwise_fma(wa, hh, U[jp]);
            DU[jp]   = __builtin_elementwise_fma(wa, pp, DU[jp]);
            U[jp+1]  = __builtin_elementwise_fma(wb, hh, U[jp+1]);
            DU[jp+1] = __builtin_elementwise_fma(wb, pp, DU[jp+1]);
        }
    }
    float z = b3v, dz = 0.0f;
#pragma unroll
    for (int jp = 0; jp < 8; ++jp)
#pragma unroll
        for (int k = 0; k < 2; ++k) {
            float u  = U[jp][k];
            float du = DU[jp][k];
            float t0 = fast_tanh(u);
            float s  = fmaf(-t0, t0, 1.0f);
            float w3 = mw.w3v[2*jp+k];
            z  = fmaf(t0, w3, z);
            dz = fmaf(s * du, w3, dz);
        }
    float az  = fabsf(z);
    float em  = __builtin_amdgcn_exp2f(-az * L2E);
    float sp  = fmaxf(z, 0.0f) + __builtin_amdgcn_logf(1.0f + em) * LN2;
    float sig = __builtin_amdgcn_rcpf(1.0f + __builtin_amdgcn_exp2f(-z * L2E));
    float g   = sp + METRIC_FLOOR;
    return 0.5f * (sig * dz) * __builtin_amdgcn_rcpf(g);
}

// ---------------------------------------------------------------------------
// K1: raw Gamma grid (NR x NR) + sqrt(g) grid (NS x NS).
// ---------------------------------------------------------------------------
extern "C" __global__ void table_raw_kernel(
    const float* __restrict__ W1, const float* __restrict__ b1,
    const float* __restrict__ W2, const float* __restrict__ b2,
    const float* __restrict__ W3, const float* __restrict__ b3,
    float* __restrict__ ws)
{
    __shared__ __align__(16) float sW2[256];
    const int t = threadIdx.x;
    sW2[t] = W2[t];
    __syncthreads();

    const int p = blockIdx.x * 256 + t;
    if (p >= NR2 + NS2) return;

    MW mw;
#pragma unroll
    for (int j = 0; j < 16; ++j) {
        mw.w1c[j] = W1[j];
        mw.w1l[j] = W1[16 + j];
        mw.b1v[j] = b1[j];
        mw.b2v[j] = b2[j];
        mw.w3v[j] = W3[j];
    }
    const float b3v = b3[0];

    if (p < NR2) {
        const int j = p / NR, i = p - j * NR;
        const float c   = (float)(i - 2) / SCALE_G;
        const float lam = (float)(j - 2) / SCALE_G;
        ws[WS_RAW + p] = gamma1(c, lam, mw, sW2, b3v);
    } else {
        const int q = p - NR2;
        const int j = q / NS, i = q - j * NS;
        const float c   = (float)i / SCALE_S;
        const float lam = (float)j / SCALE_S;
        ws[WS_SG + q] = sqrtf(metric0(c, lam, mw, sW2, b3v));
    }
}

// ---------------------------------------------------------------------------
// K2: assemble Hermite float4 (f, f_c, f_lam, f_clam) via central differences.
// ---------------------------------------------------------------------------
extern "C" __global__ void table_hermite_kernel(float* __restrict__ ws)
{
    const int p = blockIdx.x * 256 + threadIdx.x;
    if (p >= NG * NG) return;
    const int j = p / NG, i = p - j * NG;
    const int ri = i + 1, rj = j + 1;
    const float* R = ws + WS_RAW;

    float f   = R[rj * NR + ri];
    float fc  = 0.5f  * (R[rj * NR + ri + 1] - R[rj * NR + ri - 1]);
    float fl  = 0.5f  * (R[(rj + 1) * NR + ri] - R[(rj - 1) * NR + ri]);
    float fcl = 0.25f * (R[(rj + 1) * NR + ri + 1] - R[(rj + 1) * NR + ri - 1]
                       - R[(rj - 1) * NR + ri + 1] + R[(rj - 1) * NR + ri - 1]);
    float4* H = reinterpret_cast<float4*>(ws + WS_H4);
    H[p] = make_float4(f, fc, fl, fcl);
}

// ---------------------------------------------------------------------------
// Bicubic Hermite eval: 4 aligned float4 LDS reads + ~27 FMA.
// ---------------------------------------------------------------------------
static __device__ __forceinline__ float heval(
    const float4* __restrict__ r0, const float4* __restrict__ r1,
    float hy0, float hy1, float hy2, float hy3, float x)
{
    float sx = fmaf(x, SCALE_G, 1.0f);
    float fx = floorf(sx);
    fx = fminf(fmaxf(fx, 0.0f), (float)(NG - 2));
    float tx = sx - fx;
    int i0 = (int)fx;
    float t2 = tx * tx, t3 = t2 * tx;
    float hx0 = fmaf(2.0f, t3, fmaf(-3.0f, t2, 1.0f));
    float hx1 = t3 - 2.0f * t2 + tx;
    float hx2 = fmaf(-2.0f, t3, 3.0f * t2);
    float hx3 = t3 - t2;
    float4 p00 = r0[i0], p10 = r0[i0 + 1];
    float4 p01 = r1[i0], p11 = r1[i0 + 1];
    float A0 = fmaf(hx0, p00.x, fmaf(hx1, p00.y, fmaf(hx2, p10.x, hx3 * p10.y)));
    float B0 = fmaf(hx0, p00.z, fmaf(hx1, p00.w, fmaf(hx2, p10.z, hx3 * p10.w)));
    float A1 = fmaf(hx0, p01.x, fmaf(hx1, p01.y, fmaf(hx2, p11.x, hx3 * p11.y)));
    float B1 = fmaf(hx0, p01.z, fmaf(hx1, p01.w, fmaf(hx2, p11.z, hx3 * p11.w)));
    return fmaf(hy0, A0, fmaf(hy1, B0, fmaf(hy2, A1, hy3 * B1)));
}

// Bilinear sqrt(g)
static __device__ __forceinline__ float seval(
    const float* __restrict__ s0, const float* __restrict__ s1,
    float ty, float x)
{
    float sx = x * SCALE_S;
    float fx = fminf(fmaxf(floorf(sx), 0.0f), SCALE_S - 1.0f);
    float tx = sx - fx;
    int i0 = (int)fx;
    float a = fmaf(tx, s0[i0 + 1] - s0[i0], s0[i0]);
    float b = fmaf(tx, s1[i0 + 1] - s1[i0], s1[i0]);
    return fmaf(ty, b - a, a);
}

// ---------------------------------------------------------------------------
// Main kernel: pipelined staging + table-driven integration + decoder.
// ---------------------------------------------------------------------------
extern "C" __global__ __launch_bounds__(256, 1)
void geodesic_kernel(const float* __restrict__ gc0, const float* __restrict__ gc1,
                     const float* __restrict__ glam,
                     const float* __restrict__ D1, const float* __restrict__ d1,
                     const float* __restrict__ D2, const float* __restrict__ d2,
                     const float* __restrict__ ws,
                     float* __restrict__ out, int n)
{
    __shared__ __align__(16) float4 sH[NG * NG];   // 50.2 KB
    __shared__ __align__(16) float  sS[NS2];       //  9.2 KB
    __shared__ __align__(16) float  sD1[6 * 64];
    __shared__ __align__(16) float  sd1[64];
    __shared__ __align__(16) float  sD2[64];

    const int t = threadIdx.x;

    // ---- Pipelined staging: issue ALL independent global loads first, ----
    // ---- then all LDS writes, then one barrier (one latency round-trip). ----
    {
        const float4* wsH4 = reinterpret_cast<const float4*>(ws + WS_H4);
        const float4* wsS4 = reinterpret_cast<const float4*>(ws + WS_SG);
        const float4* D1f  = reinterpret_cast<const float4*>(D1);
        const float4* d1f  = reinterpret_cast<const float4*>(d1);
        const float4* D2f  = reinterpret_cast<const float4*>(D2);

        float4 hbuf[12];
#pragma unroll
        for (int k = 0; k < 12; ++k) hbuf[k] = wsH4[k * 256 + t];     // 3072
        float4 sbuf[2];
#pragma unroll
        for (int k = 0; k < 2; ++k) sbuf[k] = wsS4[k * 256 + t];      // 512
        float4 tail_h = make_float4(0.f, 0.f, 0.f, 0.f);
        float4 tail_s = tail_h, tail_d = tail_h;
        if (t < 64)  tail_h = wsH4[3072 + t];                         // 3136 total
        if (t < 64)  tail_s = wsS4[512 + t];                          // 576 total
        if (t < 128) tail_d = (t < 96) ? D1f[t]
                             : (t < 112 ? d1f[t - 96] : D2f[t - 112]);

        float4* sSf  = reinterpret_cast<float4*>(sS);
        float4* sD1f = reinterpret_cast<float4*>(sD1);
        float4* sd1f = reinterpret_cast<float4*>(sd1);
        float4* sD2f = reinterpret_cast<float4*>(sD2);
#pragma unroll
        for (int k = 0; k < 12; ++k) sH[k * 256 + t] = hbuf[k];
#pragma unroll
        for (int k = 0; k < 2; ++k) sSf[k * 256 + t] = sbuf[k];
        if (t < 64)  sH[3072 + t] = tail_h;
        if (t < 64)  sSf[512 + t] = tail_s;
        if (t < 128) {
            if (t < 96)       sD1f[t]       = tail_d;
            else if (t < 112) sd1f[t - 96]  = tail_d;
            else              sD2f[t - 112] = tail_d;
        }
    }
    __syncthreads();

    const int idx = blockIdx.x * blockDim.x + t;
    if (idx >= n) return;

    const float d2v = d2[0];
    const float c0  = gc0[idx];
    const float c1  = gc1[idx];
    const float lam = glam[idx];

    // Hoist lam-direction Hermite row + weights.
    float sy = fmaf(lam, SCALE_G, 1.0f);
    float fy = fminf(fmaxf(floorf(sy), 0.0f), (float)(NG - 2));
    float ty = sy - fy;
    int j0 = (int)fy;
    float ty2 = ty * ty, ty3 = ty2 * ty;
    const float hy0 = fmaf(2.0f, ty3, fmaf(-3.0f, ty2, 1.0f));
    const float hy1 = ty3 - 2.0f * ty2 + ty;
    const float hy2 = fmaf(-2.0f, ty3, 3.0f * ty2);
    const float hy3 = ty3 - ty2;
    const float4* gr0 = sH + j0 * NG;
    const float4* gr1 = gr0 + NG;

    // Hoist lam row for sqrt(g) bilinear.
    float syl = lam * SCALE_S;
    float fyl = fminf(fmaxf(floorf(syl), 0.0f), SCALE_S - 1.0f);
    float tyl = syl - fyl;
    const float* sr0 = sS + (int)fyl * NS;
    const float* sr1 = sr0 + NS;

    const float dt  = 1.0f / (float)(NPTS - 1);
    const float hdt = 0.5f * dt;
    const float dt6 = dt / 6.0f;

    // ---------------- Analytic init: sqrt(g)*v conserved --------------------
    const float mqm = 0.5f * (c0 + c1), mqr = 0.5f * (c1 - c0);
    float K;
    {
        const float x0 = 0.1834346424956498f, w0 = 0.3626837833783620f;
        const float x1 = 0.5255324099163290f, w1 = 0.3137066458778873f;
        const float x2 = 0.7966664774136267f, w2 = 0.2223810344533745f;
        const float x3 = 0.9602898564975363f, w3q = 0.1012285362903763f;
        float s0 = seval(sr0, sr1, tyl, fmaf(mqr,  x0, mqm))
                 + seval(sr0, sr1, tyl, fmaf(mqr, -x0, mqm));
        float s1 = seval(sr0, sr1, tyl, fmaf(mqr,  x1, mqm))
                 + seval(sr0, sr1, tyl, fmaf(mqr, -x1, mqm));
        float s2 = seval(sr0, sr1, tyl, fmaf(mqr,  x2, mqm))
                 + seval(sr0, sr1, tyl, fmaf(mqr, -x2, mqm));
        float s3 = seval(sr0, sr1, tyl, fmaf(mqr,  x3, mqm))
                 + seval(sr0, sr1, tyl, fmaf(mqr, -x3, mqm));
        K = w0 * s0 + w1 * s1 + w2 * s2 + w3q * s3;
    }
    const float sg0 = seval(sr0, sr1, tyl, c0);
    const float v0i = (mqr * K) * __builtin_amdgcn_rcpf(sg0);

    // ---------------- Single RK4 pass + stats + sensitivity accumulators ----
    float csum, vsum, plen, vmax, cf, vf, cs2, va;
    {
        float c = c0, v = v0i;
        float cs = c0, vs = v0i, pl = 0.0f, vm = fabsf(v0i), cp = c0;
        float c2sum = 0.0f, vasum = 0.0f, k4v_last = 0.0f;
#pragma unroll 1
        for (int s = 0; s < NSTEPS; ++s) {
            float G1 = heval(gr0, gr1, hy0, hy1, hy2, hy3, c);
            float k1c = v, k1v = -G1 * v * v;
            vasum = fmaf((float)s * dt, k1v, vasum);      // t_s * a_s
            float c2 = c + hdt * k1c, v2 = v + hdt * k1v;
            float G2 = heval(gr0, gr1, hy0, hy1, hy2, hy3, c2);
            float k2c = v2, k2v = -G2 * v2 * v2;
            float c3 = c + hdt * k2c, v3 = v + hdt * k2v;
            float G3 = heval(gr0, gr1, hy0, hy1, hy2, hy3, c3);
            float k3c = v3, k3v = -G3 * v3 * v3;
            float c4 = c + dt * k3c, v4 = v + dt * k3v;
            float G4 = heval(gr0, gr1, hy0, hy1, hy2, hy3, c4);
            float k4c = v4, k4v = -G4 * v4 * v4;
            c += dt6 * (k1c + 2.0f * k2c + 2.0f * k3c + k4c);
            v += dt6 * (k1v + 2.0f * k2v + 2.0f * k3v + k4v);
            cs += c; vs += v;
            c2sum = fmaf((float)(s + 1) * dt, v, c2sum);  // t_{s+1} * v_{s+1}
            pl += fabsf(c - cp); cp = c;
            vm = fmaxf(vm, fabsf(v));
            k4v_last = k4v;
        }
        vasum += k4v_last;                                // t_10 = 1, a_10 ~ k4v
        csum = cs; vsum = vs; plen = pl; vmax = vm; cf = c; vf = v;
        cs2 = c2sum; va = vasum;
    }

    // ---------------- First-order correction to the Newton root -------------
    float vf_safe = (fabsf(vf) < 1e-6f) ? ((vf >= 0.0f) ? 1e-6f : -1e-6f) : vf;
    float eps = (c1 - cf) * __builtin_amdgcn_rcpf(vf_safe);
    float csum_c = fmaf(eps, cs2, csum);
    float vsum_c = fmaf(eps, vsum + va, vsum);
    float plen_c = plen + ((vf >= 0.0f) ? (c1 - cf) : (cf - c1));
    float vmax_c = fmaf(eps, vmax, vmax);
    float cf_c   = cf + eps * vf_safe;                    // == c1

    // ---------------- Decoder: feats(6) -> 64 tanh -> 1 ----------------
    const float inv_npts = 1.0f / (float)NPTS;
    const float f0 = csum_c * inv_npts;
    const float f1 = cf_c;
    const float f2 = plen_c;
    const float f3 = vsum_c * inv_npts;
    const float f4 = vmax_c;
    const float f5 = lam;

    float acc = d2v;
#pragma unroll 4
    for (int j = 0; j < 64; ++j) {
        float u = sd1[j];
        u = fmaf(f0, sD1[0 * 64 + j], u);
        u = fmaf(f1, sD1[1 * 64 + j], u);
        u = fmaf(f2, sD1[2 * 64 + j], u);
        u = fmaf(f3, sD1[3 * 64 + j], u);
        u = fmaf(f4, sD1[4 * 64 + j], u);
        u = fmaf(f5, sD1[5 * 64 + j], u);
        acc = fmaf(fast_tanh(u), sD2[j], acc);
    }
    out[idx] = acc;
}

extern "C" void kernel_launch(void* const* d_in, const int* in_sizes, int n_in,
                              void* d_out, int out_size, void* d_ws, size_t ws_size,
                              hipStream_t stream) {
    const float* c_source   = (const float*)d_in[0];
    const float* c_target   = (const float*)d_in[1];
    const float* wavelength = (const float*)d_in[2];
    const float* W1 = (const float*)d_in[3];
    const float* b1 = (const float*)d_in[4];
    const float* W2 = (const float*)d_in[5];
    const float* b2 = (const float*)d_in[6];
    const float* W3 = (const float*)d_in[7];
    const float* b3 = (const float*)d_in[8];
    const float* D1 = (const float*)d_in[9];
    const float* d1 = (const float*)d_in[10];
    const float* D2 = (const float*)d_in[11];
    const float* d2 = (const float*)d_in[12];
    float* out = (float*)d_out;
    float* ws  = (float*)d_ws;

    const int n = in_sizes[0];

    // K1: raw Gamma grid + sqrt(g) grid.
    const int p1 = NR2 + NS2;
    hipLaunchKernelGGL(table_raw_kernel, dim3((p1 + 255) / 256), dim3(256), 0,
                       stream, W1, b1, W2, b2, W3, b3, ws);
    // K2: Hermite float4 assembly.
    hipLaunchKernelGGL(table_hermite_kernel, dim3((NG * NG + 255) / 256),
                       dim3(256), 0, stream, ws);
    // Main.
    const int block = 256;
    const int grid  = (n + block - 1) / block;
    hipLaunchKernelGGL(geodesic_kernel, dim3(grid), dim3(block), 0, stream,
                       c_source, c_target, wavelength,
                       D1, d1, D2, d2, ws, out, n);
}